// Round 1
// baseline (350.282 us; speedup 1.0000x reference)
//
#include <hip/hip_runtime.h>
#include <cstdint>
#include <cstddef>

// Mask R-CNN detection post-processing: bbox_transform -> per-class NMS (K=81)
// -> per-row max/argmax -> global top-100 selection.
// All sorts implemented as exact stable ranks to match JAX argsort tie-breaking.

#define R 512
#define K 81
#define IM_W_MAX 1332.0f   // IM_W - 1
#define IM_H_MAX 799.0f    // IM_H - 1
#define XFORM_CLIP_F 4.135166556742356f  // log(1000/16)
#define NMS_THRESH_F 0.5f
#define SCORE_THRESH_F 0.001f
#define MAX_PER_IMG 100
#define POST_NMS_TOPN 300
#define NMS_THREADS 256

// ---------------------------------------------------------------------------
// Kernel 1: bbox_transform.  boxes3[(r*K + k)*4 + c]
// ---------------------------------------------------------------------------
__global__ void bbox_transform_kernel(const float* __restrict__ rois,
                                      const float* __restrict__ deltas,
                                      float* __restrict__ boxes3) {
    int idx = blockIdx.x * blockDim.x + threadIdx.x;
    if (idx >= R * K) return;
    int r = idx / K;
    int k = idx - r * K;
    float x1 = rois[r * 4 + 0], y1 = rois[r * 4 + 1];
    float x2 = rois[r * 4 + 2], y2 = rois[r * 4 + 3];
    float w  = x2 - x1 + 1.0f;
    float h  = y2 - y1 + 1.0f;
    float cx = x1 + 0.5f * w;
    float cy = y1 + 0.5f * h;
    const float* d = deltas + (size_t)r * (4 * K) + k * 4;
    float dx = d[0] / 10.0f;                       // WX
    float dy = d[1] / 10.0f;                       // WY
    float dw = fminf(d[2] / 5.0f, XFORM_CLIP_F);   // WW
    float dh = fminf(d[3] / 5.0f, XFORM_CLIP_F);   // WH
    float pcx = dx * w + cx;
    float pcy = dy * h + cy;
    float pw  = expf(dw) * w;
    float ph  = expf(dh) * h;
    float o0 = fminf(fmaxf(pcx - 0.5f * pw, 0.0f), IM_W_MAX);
    float o1 = fminf(fmaxf(pcy - 0.5f * ph, 0.0f), IM_H_MAX);
    float o2 = fminf(fmaxf(pcx + 0.5f * pw - 1.0f, 0.0f), IM_W_MAX);
    float o3 = fminf(fmaxf(pcy + 0.5f * ph - 1.0f, 0.0f), IM_H_MAX);
    float* o = boxes3 + (size_t)idx * 4;
    o[0] = o0; o[1] = o1; o[2] = o2; o[3] = o3;
}

// ---------------------------------------------------------------------------
// Kernel 2: per-class NMS.  One block per class.
// dists[r*K + k] = score if (class valid && box kept) else 0
// ---------------------------------------------------------------------------
__global__ void __launch_bounds__(NMS_THREADS)
nms_kernel(const float* __restrict__ scores,
           const float* __restrict__ boxes3,
           float* __restrict__ dists) {
    const int k   = blockIdx.x;
    const int tid = threadIdx.x;

    __shared__ float s_sc[R];          // scores by ORIGINAL index
    __shared__ int   s_order[R];       // order[rank] = original index
    __shared__ float s_x1[R], s_y1[R], s_x2[R], s_y2[R], s_area[R];  // sorted
    __shared__ unsigned long long s_sup[R * 8];   // 32 KB suppression bitmatrix
    __shared__ unsigned long long s_keep[8];
    __shared__ int   s_valid;
    __shared__ float s_red[NMS_THREADS];

    // Load this class's scores.
    for (int i = tid; i < R; i += NMS_THREADS) s_sc[i] = scores[i * K + k];
    __syncthreads();

    // Class validity: k != 0 && max(scores) > SCORE_THRESH (strict).
    float m = -1.0f;
    for (int i = tid; i < R; i += NMS_THREADS) m = fmaxf(m, s_sc[i]);
    s_red[tid] = m;
    __syncthreads();
    for (int s = NMS_THREADS / 2; s > 0; s >>= 1) {
        if (tid < s) s_red[tid] = fmaxf(s_red[tid], s_red[tid + s]);
        __syncthreads();
    }
    if (tid == 0) s_valid = (k != 0) && (s_red[0] > SCORE_THRESH_F);
    __syncthreads();
    if (!s_valid) {
        for (int i = tid; i < R; i += NMS_THREADS) dists[i * K + k] = 0.0f;
        return;
    }

    // Stable descending rank-sort (matches jnp.argsort(-s) exactly).
    for (int i = tid; i < R; i += NMS_THREADS) {
        float si = s_sc[i];
        int cnt = 0;
        for (int j = 0; j < R; ++j) {
            float sj = s_sc[j];
            cnt += (sj > si) || (sj == si && j < i);
        }
        s_order[cnt] = i;
    }
    __syncthreads();

    // Gather boxes in sorted order; areas on sorted boxes.
    for (int rk = tid; rk < R; rk += NMS_THREADS) {
        int orig = s_order[rk];
        const float* b = boxes3 + ((size_t)orig * K + k) * 4;
        float bx1 = b[0], by1 = b[1], bx2 = b[2], by2 = b[3];
        s_x1[rk] = bx1; s_y1[rk] = by1; s_x2[rk] = bx2; s_y2[rk] = by2;
        s_area[rk] = (bx2 - bx1 + 1.0f) * (by2 - by1 + 1.0f);
    }
    __syncthreads();

    // Suppression bitmatrix: s_sup[i*8+w] bit jj set iff j=w*64+jj > i and
    // IoU(i,j) > 0.5.  Same arithmetic order as reference: (a_i + a_j) - inter.
    for (int t = tid; t < R * 8; t += NMS_THREADS) {
        int i = t >> 3;
        int w = t & 7;
        float xi1 = s_x1[i], yi1 = s_y1[i], xi2 = s_x2[i], yi2 = s_y2[i];
        float ai = s_area[i];
        unsigned long long bits = 0ull;
        int jbase = w * 64;
        for (int jj = 0; jj < 64; ++jj) {
            int j = jbase + jj;
            if (j <= i) continue;
            float xx1 = fmaxf(xi1, s_x1[j]);
            float yy1 = fmaxf(yi1, s_y1[j]);
            float xx2 = fminf(xi2, s_x2[j]);
            float yy2 = fminf(yi2, s_y2[j]);
            float iw = fmaxf(xx2 - xx1 + 1.0f, 0.0f);
            float ih = fmaxf(yy2 - yy1 + 1.0f, 0.0f);
            float inter = iw * ih;
            float iou = inter / (ai + s_area[j] - inter);
            if (iou > NMS_THRESH_F) bits |= (1ull << jj);
        }
        s_sup[i * 8 + w] = bits;
    }
    __syncthreads();

    // Serial greedy sweep + inclusive-cumsum <= 300 cut (thread 0; ~4k ops).
    if (tid == 0) {
        unsigned long long kb[8];
        for (int w = 0; w < 8; ++w) kb[w] = ~0ull;
        for (int i = 0; i < R; ++i) {
            if ((kb[i >> 6] >> (i & 63)) & 1ull) {
                const unsigned long long* srow = &s_sup[i * 8];
                for (int w = 0; w < 8; ++w) kb[w] &= ~srow[w];
            }
        }
        int cnt = 0;
        for (int i = 0; i < R; ++i) {
            if ((kb[i >> 6] >> (i & 63)) & 1ull) {
                if (++cnt > POST_NMS_TOPN) kb[i >> 6] &= ~(1ull << (i & 63));
            }
        }
        for (int w = 0; w < 8; ++w) s_keep[w] = kb[w];
    }
    __syncthreads();

    // Scatter back to original index order; fold in score multiply (mask*s).
    for (int rk = tid; rk < R; rk += NMS_THREADS) {
        int orig = s_order[rk];
        bool kept = (s_keep[rk >> 6] >> (rk & 63)) & 1ull;
        dists[orig * K + k] = kept ? s_sc[orig] : 0.0f;
    }
}

// ---------------------------------------------------------------------------
// Kernel 3: per-row max/first-argmax, stable top-100 selection, output write.
// Output layout (700 floats): [0..499] out(100x5), [500..599] labels,
// [600..699] top (ints written as floats).
// ---------------------------------------------------------------------------
__global__ void __launch_bounds__(R)
finalize_kernel(const float* __restrict__ dists,
                const float* __restrict__ boxes3,
                float* __restrict__ out) {
    const int r = threadIdx.x;   // one thread per roi, 512 threads
    __shared__ float s_pre[R];

    const float* dr = dists + (size_t)r * K;
    float vmax = dr[0];
    int arg = 0;
    for (int kk = 1; kk < K; ++kk) {
        float v = dr[kk];
        if (v > vmax) { vmax = v; arg = kk; }   // first-occurrence argmax
    }
    s_pre[r] = vmax;
    __syncthreads();

    // Stable descending rank (matches jnp.argsort(-scores_pre)).
    int cnt = 0;
    for (int j = 0; j < R; ++j) {
        float sj = s_pre[j];
        cnt += (sj > vmax) || (sj == vmax && j < r);
    }
    if (cnt < MAX_PER_IMG) {
        bool valid = vmax > SCORE_THRESH_F;
        out[cnt * 5 + 0] = valid ? vmax : 0.0f;
        const float* b = boxes3 + ((size_t)r * K + arg) * 4;
        out[cnt * 5 + 1] = valid ? b[0] : 0.0f;
        out[cnt * 5 + 2] = valid ? b[1] : 0.0f;
        out[cnt * 5 + 3] = valid ? b[2] : 0.0f;
        out[cnt * 5 + 4] = valid ? b[3] : 0.0f;
        out[500 + cnt] = (float)arg;   // labels_all
        out[600 + cnt] = (float)r;     // top
    }
}

// ---------------------------------------------------------------------------
extern "C" void kernel_launch(void* const* d_in, const int* in_sizes, int n_in,
                              void* d_out, int out_size, void* d_ws, size_t ws_size,
                              hipStream_t stream) {
    const float* rois   = (const float*)d_in[0];   // [512,4]
    const float* deltas = (const float*)d_in[1];   // [512,324]
    const float* scores = (const float*)d_in[2];   // [512,81]
    float* out = (float*)d_out;                    // 700 floats

    // Workspace: boxes3 (R*K*4 floats = 663552 B) + dists (R*K floats = 165888 B)
    float* boxes3 = (float*)d_ws;
    float* dists  = boxes3 + (size_t)R * K * 4;

    bbox_transform_kernel<<<(R * K + 255) / 256, 256, 0, stream>>>(rois, deltas, boxes3);
    nms_kernel<<<K, NMS_THREADS, 0, stream>>>(scores, boxes3, dists);
    finalize_kernel<<<1, R, 0, stream>>>(dists, boxes3, out);
}

// Round 2
// 208.340 us; speedup vs baseline: 1.6813x; 1.6813x over previous
//
#include <hip/hip_runtime.h>
#include <cstdint>
#include <cstddef>

// Mask R-CNN detection post-processing, fused:
//   Kernel 1 (81 blocks): bbox_transform (per class) + stable rank-sort +
//                         IoU suppression bitmatrix + serial greedy sweep
//                         (register-only, static indexing) + top-300 cut.
//   Kernel 2 (1 block):   per-row max/first-argmax, stable top-100 rank,
//                         box recompute, output write.
// All sorts are exact stable ranks to match JAX argsort tie-breaking.

#define R 512
#define K 81
#define IM_W_MAX 1332.0f   // IM_W - 1
#define IM_H_MAX 799.0f    // IM_H - 1
#define XFORM_CLIP_F 4.135166556742356f  // log(1000/16)
#define NMS_THRESH_F 0.5f
#define SCORE_THRESH_F 0.001f
#define MAX_PER_IMG 100
#define POST_NMS_TOPN 300
#define NMS_THREADS 256

// Box transform for (roi r, class k) — expressions must stay IDENTICAL in
// both kernels (round-1 verified absmax 0.0 against the np reference).
__device__ __forceinline__ float4 transform_box(const float* __restrict__ rois,
                                                const float* __restrict__ deltas,
                                                int r, int k) {
    float rx1 = rois[r * 4 + 0], ry1 = rois[r * 4 + 1];
    float rx2 = rois[r * 4 + 2], ry2 = rois[r * 4 + 3];
    float w  = rx2 - rx1 + 1.0f;
    float h  = ry2 - ry1 + 1.0f;
    float cx = rx1 + 0.5f * w;
    float cy = ry1 + 0.5f * h;
    const float* d = deltas + (size_t)r * (4 * K) + 4 * k;
    float dx = d[0] / 10.0f;                       // WX
    float dy = d[1] / 10.0f;                       // WY
    float dw = fminf(d[2] / 5.0f, XFORM_CLIP_F);   // WW
    float dh = fminf(d[3] / 5.0f, XFORM_CLIP_F);   // WH
    float pcx = dx * w + cx;
    float pcy = dy * h + cy;
    float pw  = expf(dw) * w;
    float ph  = expf(dh) * h;
    float4 b;
    b.x = fminf(fmaxf(pcx - 0.5f * pw, 0.0f), IM_W_MAX);
    b.y = fminf(fmaxf(pcy - 0.5f * ph, 0.0f), IM_H_MAX);
    b.z = fminf(fmaxf(pcx + 0.5f * pw - 1.0f, 0.0f), IM_W_MAX);
    b.w = fminf(fmaxf(pcy + 0.5f * ph - 1.0f, 0.0f), IM_H_MAX);
    return b;
}

// ---------------------------------------------------------------------------
// Kernel 1: fused per-class NMS. One block per class.
// dists_t[k*R + r] = score if (class valid && box kept) else 0.
// ---------------------------------------------------------------------------
__global__ void __launch_bounds__(NMS_THREADS)
nms_fused_kernel(const float* __restrict__ rois,
                 const float* __restrict__ deltas,
                 const float* __restrict__ scores,
                 float* __restrict__ dists_t) {
    const int k   = blockIdx.x;
    const int tid = threadIdx.x;

    __shared__ float  s_sc[R];                    // scores by original index
    __shared__ int    s_order[R];                 // order[rank] = original idx
    __shared__ float4 s_obox[R];                  // boxes by original index
    __shared__ float4 s_sbox[R];                  // boxes in sorted order
    __shared__ unsigned long long s_sup[R * 8];   // 32 KB suppression bitmatrix
    __shared__ unsigned long long s_keep[8];
    __shared__ float  s_red[NMS_THREADS];

    // Phase 1: load scores + compute boxes for this class (2 rois/thread).
    for (int i = tid; i < R; i += NMS_THREADS) {
        s_sc[i]   = scores[i * K + k];
        s_obox[i] = transform_box(rois, deltas, i, k);
    }
    __syncthreads();

    // Phase 2: class validity (k != 0 && max score > thresh, strict).
    float m = -1.0f;
    for (int i = tid; i < R; i += NMS_THREADS) m = fmaxf(m, s_sc[i]);
    s_red[tid] = m;
    __syncthreads();
    for (int s = NMS_THREADS / 2; s > 0; s >>= 1) {
        if (tid < s) s_red[tid] = fmaxf(s_red[tid], s_red[tid + s]);
        __syncthreads();
    }
    bool cls_valid = (k != 0) && (s_red[0] > SCORE_THRESH_F);
    if (!cls_valid) {   // uniform across block
        for (int i = tid; i < R; i += NMS_THREADS) dists_t[k * R + i] = 0.0f;
        return;
    }

    // Phase 3: stable descending rank-sort (== jnp.argsort(-s)).
    {
        const int i0 = tid, i1 = tid + NMS_THREADS;
        float si0 = s_sc[i0], si1 = s_sc[i1];
        int c0 = 0, c1 = 0;
        for (int j = 0; j < R; ++j) {
            float sj = s_sc[j];
            c0 += (sj > si0) || (sj == si0 && j < i0);
            c1 += (sj > si1) || (sj == si1 && j < i1);
        }
        s_order[c0] = i0;
        s_order[c1] = i1;
    }
    __syncthreads();

    // Phase 4: gather boxes into sorted order.
    for (int rk = tid; rk < R; rk += NMS_THREADS) s_sbox[rk] = s_obox[s_order[rk]];
    __syncthreads();

    // Phase 5: suppression bitmatrix. Thread handles i = tid and i = 511-tid
    // (balanced upper-triangle work). All lanes broadcast-read the same j
    // box — conflict-free LDS.
    for (int rep = 0; rep < 2; ++rep) {
        const int i = (rep == 0) ? tid : (R - 1 - tid);
        const float4 bi = s_sbox[i];
        const float ai = (bi.z - bi.x + 1.0f) * (bi.w - bi.y + 1.0f);
        #pragma unroll
        for (int w = 0; w < 8; ++w) {
            const int jbase = w * 64;
            const int d = i - jbase;
            if (d >= 63) { s_sup[i * 8 + w] = 0ull; continue; }  // word all j<=i
            unsigned long long bits = 0ull;
            for (int jj = 0; jj < 64; ++jj) {
                float4 bj = s_sbox[jbase + jj];
                float aj = (bj.z - bj.x + 1.0f) * (bj.w - bj.y + 1.0f);
                float xx1 = fmaxf(bi.x, bj.x);
                float yy1 = fmaxf(bi.y, bj.y);
                float xx2 = fminf(bi.z, bj.z);
                float yy2 = fminf(bi.w, bj.w);
                float iw = fmaxf(xx2 - xx1 + 1.0f, 0.0f);
                float ih = fmaxf(yy2 - yy1 + 1.0f, 0.0f);
                float inter = iw * ih;
                float iou = inter / (ai + aj - inter);
                bits |= (unsigned long long)(iou > NMS_THRESH_F) << jj;
            }
            unsigned long long mask = (d < 0) ? ~0ull : (~0ull << (d + 1));
            s_sup[i * 8 + w] = bits & mask;
        }
    }
    __syncthreads();

    // Phase 6: serial greedy sweep + top-300 cut on wave 0 only.
    // keep-mask lives entirely in registers: every index into kb[] is
    // compile-time constant after unrolling (NO scratch — round-1's bug).
    if (tid < 64) {
        unsigned long long kb[8];
        #pragma unroll
        for (int w = 0; w < 8; ++w) kb[w] = ~0ull;

        #pragma unroll
        for (int wb = 0; wb < 8; ++wb) {
            for (int bit = 0; bit < 64; ++bit) {      // dynamic loop, uniform
                const int i = wb * 64 + bit;
                // Row words < wb are all zero (j<=i masked) — skip them.
                unsigned long long row[8];
                #pragma unroll
                for (int w = wb; w < 8; ++w) row[w] = s_sup[i * 8 + w];
                if ((kb[wb] >> bit) & 1ull) {
                    #pragma unroll
                    for (int w = wb; w < 8; ++w) kb[w] &= ~row[w];
                }
            }
        }

        // cumsum(keep) <= 300 cut, in sorted-rank order.
        int total = 0;
        #pragma unroll
        for (int w = 0; w < 8; ++w) total += __popcll(kb[w]);
        if (total > POST_NMS_TOPN) {
            int cnt = 0;
            #pragma unroll
            for (int w = 0; w < 8; ++w) {
                unsigned long long word = kb[w], outw = 0ull;
                for (int bit = 0; bit < 64; ++bit) {
                    if ((word >> bit) & 1ull) {
                        if (cnt < POST_NMS_TOPN) outw |= 1ull << bit;
                        ++cnt;
                    }
                }
                kb[w] = outw;
            }
        }
        if (tid == 0) {
            #pragma unroll
            for (int w = 0; w < 8; ++w) s_keep[w] = kb[w];
        }
    }
    __syncthreads();

    // Phase 7: scatter to original index order, fold in mask*score.
    for (int rk = tid; rk < R; rk += NMS_THREADS) {
        int orig = s_order[rk];
        bool kept = (s_keep[rk >> 6] >> (rk & 63)) & 1ull;
        dists_t[k * R + orig] = kept ? s_sc[orig] : 0.0f;
    }
}

// ---------------------------------------------------------------------------
// Kernel 2: per-row max/first-argmax, stable top-100, box recompute, output.
// Output layout (700 floats): [0..499] out(100x5), [500..599] labels,
// [600..699] top indices (ints as floats).
// ---------------------------------------------------------------------------
__global__ void __launch_bounds__(R)
finalize_kernel(const float* __restrict__ dists_t,
                const float* __restrict__ rois,
                const float* __restrict__ deltas,
                float* __restrict__ out) {
    const int r = threadIdx.x;   // one thread per roi
    __shared__ float s_pre[R];

    float vmax = dists_t[r];     // kk = 0 (always 0, class 0 invalid — but
    int arg = 0;                 // matches reference argmax over full row)
    for (int kk = 1; kk < K; ++kk) {
        float v = dists_t[kk * R + r];        // coalesced across threads
        if (v > vmax) { vmax = v; arg = kk; } // first-occurrence argmax
    }
    s_pre[r] = vmax;
    __syncthreads();

    // Stable descending rank (== jnp.argsort(-scores_pre)).
    int cnt = 0;
    for (int j = 0; j < R; ++j) {
        float sj = s_pre[j];
        cnt += (sj > vmax) || (sj == vmax && j < r);
    }
    if (cnt < MAX_PER_IMG) {
        bool valid = vmax > SCORE_THRESH_F;
        float4 b = transform_box(rois, deltas, r, arg);
        out[cnt * 5 + 0] = valid ? vmax : 0.0f;
        out[cnt * 5 + 1] = valid ? b.x : 0.0f;
        out[cnt * 5 + 2] = valid ? b.y : 0.0f;
        out[cnt * 5 + 3] = valid ? b.z : 0.0f;
        out[cnt * 5 + 4] = valid ? b.w : 0.0f;
        out[500 + cnt] = (float)arg;   // labels_all
        out[600 + cnt] = (float)r;     // top
    }
}

// ---------------------------------------------------------------------------
extern "C" void kernel_launch(void* const* d_in, const int* in_sizes, int n_in,
                              void* d_out, int out_size, void* d_ws, size_t ws_size,
                              hipStream_t stream) {
    const float* rois   = (const float*)d_in[0];   // [512,4]
    const float* deltas = (const float*)d_in[1];   // [512,324]
    const float* scores = (const float*)d_in[2];   // [512,81]
    float* out = (float*)d_out;                    // 700 floats

    float* dists_t = (float*)d_ws;                 // [K][R] = 165888 B

    nms_fused_kernel<<<K, NMS_THREADS, 0, stream>>>(rois, deltas, scores, dists_t);
    finalize_kernel<<<1, R, 0, stream>>>(dists_t, rois, deltas, out);
}

// Round 3
// 164.672 us; speedup vs baseline: 2.1271x; 1.2652x over previous
//
#include <hip/hip_runtime.h>
#include <cstdint>
#include <cstddef>

// Mask R-CNN detection post-processing, single fused kernel (81 blocks x 1024):
//   per class: score load -> validity -> stable rank-sort -> boxes at sorted
//   position -> IoU suppression bitmatrix (transposed, broadcast-read) ->
//   wave-cooperative greedy sweep (registers + readlane, no serial LDS chain)
//   -> top-300 cut -> masked-score write.
//   Last block (device-scope ticket) runs the finalize: per-row max/first-
//   argmax, stable top-100 rank, box recompute, output write.
// All sorts are exact stable ranks to match JAX argsort tie-breaking; IoU uses
// IEEE f32 division in reference expression order (bit-exact, absmax 0.0 in R1/R2).

#define R 512
#define K 81
#define IM_W_MAX 1332.0f   // IM_W - 1
#define IM_H_MAX 799.0f    // IM_H - 1
#define XFORM_CLIP_F 4.135166556742356f  // log(1000/16)
#define NMS_THRESH_F 0.5f
#define SCORE_THRESH_F 0.001f
#define MAX_PER_IMG 100
#define POST_NMS_TOPN 300
#define NMS_THREADS 1024

// Box transform for (roi r, class k). Value-identical to rounds 1-2 (which
// verified absmax 0.0); float4 loads are aligned (1296r + 16k ≡ 0 mod 16).
__device__ __forceinline__ float4 transform_box(const float* __restrict__ rois,
                                                const float* __restrict__ deltas,
                                                int r, int k) {
    float4 roi = ((const float4*)rois)[r];
    float4 d4  = *(const float4*)(deltas + (size_t)r * (4 * K) + 4 * k);
    float w  = roi.z - roi.x + 1.0f;
    float h  = roi.w - roi.y + 1.0f;
    float cx = roi.x + 0.5f * w;
    float cy = roi.y + 0.5f * h;
    float dx = d4.x / 10.0f;                       // WX
    float dy = d4.y / 10.0f;                       // WY
    float dw = fminf(d4.z / 5.0f, XFORM_CLIP_F);   // WW
    float dh = fminf(d4.w / 5.0f, XFORM_CLIP_F);   // WH
    float pcx = dx * w + cx;
    float pcy = dy * h + cy;
    float pw  = expf(dw) * w;
    float ph  = expf(dh) * h;
    float4 b;
    b.x = fminf(fmaxf(pcx - 0.5f * pw, 0.0f), IM_W_MAX);
    b.y = fminf(fmaxf(pcy - 0.5f * ph, 0.0f), IM_H_MAX);
    b.z = fminf(fmaxf(pcx + 0.5f * pw - 1.0f, 0.0f), IM_W_MAX);
    b.w = fminf(fmaxf(pcy + 0.5f * ph - 1.0f, 0.0f), IM_H_MAX);
    return b;
}

__global__ void __launch_bounds__(NMS_THREADS)
nms_all_kernel(const float* __restrict__ rois,
               const float* __restrict__ deltas,
               const float* __restrict__ scores,
               float* __restrict__ dists_t,     // [K][R]
               unsigned int* __restrict__ ticket,
               float* __restrict__ out) {
    const int k   = blockIdx.x;
    const int tid = threadIdx.x;

    __shared__ float  s_sc[R];                  // scores by original index / s_pre in finalize
    __shared__ int    s_order[R];               // order[rank] = original idx / arg in finalize
    __shared__ float4 s_sbox[R];                // boxes in sorted order
    __shared__ float  s_area[R];                // areas in sorted order
    __shared__ unsigned long long s_supT[8 * R];// transposed bitmatrix [w][i], 32 KB
    __shared__ unsigned long long s_keep[8];
    __shared__ float  s_red[256];
    __shared__ int    s_last;

    // ---- Phase 1: load this class's scores (threads 0..511) ----
    if (tid < R) s_sc[tid] = scores[tid * K + k];
    __syncthreads();

    // ---- Phase 2: class validity (k != 0 && max score > thresh, strict) ----
    if (tid < 256) s_red[tid] = fmaxf(s_sc[tid], s_sc[tid + 256]);
    __syncthreads();
    for (int s = 128; s > 0; s >>= 1) {
        if (tid < s) s_red[tid] = fmaxf(s_red[tid], s_red[tid + s]);
        __syncthreads();
    }
    const bool cls_valid = (k != 0) && (s_red[0] > SCORE_THRESH_F);  // block-uniform

    if (cls_valid) {
        // ---- Phase 3: stable descending rank (== jnp.argsort(-s)) ----
        if (tid < R) {
            const float si = s_sc[tid];
            int cnt = 0;
            for (int j = 0; j < R; ++j) {
                float sj = s_sc[j];
                cnt += (sj > si) || (sj == si && j < tid);
            }
            s_order[cnt] = tid;
        }
        __syncthreads();

        // ---- Phase 4: boxes directly at sorted position ----
        if (tid < R) {
            int orig = s_order[tid];
            float4 b = transform_box(rois, deltas, orig, k);
            s_sbox[tid] = b;
            s_area[tid] = (b.z - b.x + 1.0f) * (b.w - b.y + 1.0f);
        }
        __syncthreads();

        // ---- Phase 5: suppression bitmatrix (transposed [w][i]) ----
        // Thread (i5, sel) computes words w = w0+sel, w0+sel+2, ... All lanes of
        // a wave share w0/sel -> same w each step -> broadcast LDS reads.
        {
            const int i5  = tid & (R - 1);
            const int sel = tid >> 9;
            const int w0  = i5 >> 6;
            const float4 bi = s_sbox[i5];
            const float  ai = s_area[i5];
            for (int w = w0 + sel; w < 8; w += 2) {
                const int d = i5 - w * 64;   // bits jj <= d are j <= i: masked
                unsigned long long mask =
                    (d < 0) ? ~0ull : ((d >= 63) ? 0ull : (~0ull << (d + 1)));
                unsigned long long bits = 0ull;
                #pragma unroll 8
                for (int jj = 0; jj < 64; ++jj) {
                    const int j = w * 64 + jj;
                    float4 bj = s_sbox[j];
                    float  aj = s_area[j];
                    float xx1 = fmaxf(bi.x, bj.x);
                    float yy1 = fmaxf(bi.y, bj.y);
                    float xx2 = fminf(bi.z, bj.z);
                    float yy2 = fminf(bi.w, bj.w);
                    float iw = fmaxf(xx2 - xx1 + 1.0f, 0.0f);
                    float ih = fmaxf(yy2 - yy1 + 1.0f, 0.0f);
                    float inter = iw * ih;
                    float iou = inter / (ai + aj - inter);   // IEEE div, ref order
                    bits |= (unsigned long long)(iou > NMS_THRESH_F) << jj;
                }
                s_supT[w * R + i5] = bits & mask;
            }
        }
        __syncthreads();

        // ---- Phase 6: wave-cooperative greedy sweep (wave 0 only) ----
        if (tid < 64) {
            const int l = tid;
            unsigned long long kb[8];
            #pragma unroll
            for (int w = 0; w < 8; ++w) kb[w] = ~0ull;

            #pragma unroll
            for (int wb = 0; wb < 8; ++wb) {
                // Lane l owns row i = wb*64+l; batch-load its words (one wait).
                unsigned long long rrow[8];
                #pragma unroll
                for (int w = 0; w < 8; ++w)
                    rrow[w] = (w >= wb) ? s_supT[w * R + (wb * 64 + l)] : 0ull;

                const unsigned int r_lo = (unsigned int)(rrow[wb] & 0xffffffffull);
                const unsigned int r_hi = (unsigned int)(rrow[wb] >> 32);

                // Intra-block serial sweep over still-alive bits only.
                // cur/m are wave-uniform -> readlane index is uniform.
                unsigned long long cur = kb[wb];
                unsigned long long m = cur;
                while (m) {
                    int bit = __builtin_ctzll(m);
                    unsigned long long row =
                        ((unsigned long long)(unsigned int)__builtin_amdgcn_readlane((int)r_hi, bit) << 32) |
                         (unsigned long long)(unsigned int)__builtin_amdgcn_readlane((int)r_lo, bit);
                    m &= m - 1;     // row never contains its own bit (upper-tri)
                    cur &= ~row;
                    m   &= ~row;
                }
                kb[wb] = cur;

                // Inter-block pruning: OR of kept rows' future words.
                #pragma unroll
                for (int w = wb + 1; w < 8; ++w) {
                    unsigned long long contrib = ((cur >> l) & 1ull) ? rrow[w] : 0ull;
                    #pragma unroll
                    for (int off = 32; off > 0; off >>= 1)
                        contrib |= __shfl_xor(contrib, off, 64);
                    kb[w] &= ~contrib;   // uniform after reduce
                }
            }

            // cumsum(keep) <= 300 cut, sorted-rank order.
            int total = 0;
            #pragma unroll
            for (int w = 0; w < 8; ++w) total += __popcll(kb[w]);
            if (total > POST_NMS_TOPN) {
                int cnt = 0;
                #pragma unroll
                for (int w = 0; w < 8; ++w) {
                    int pc = __popcll(kb[w]);
                    if (cnt + pc <= POST_NMS_TOPN) { cnt += pc; continue; }
                    unsigned long long word = kb[w], outw = 0ull;
                    int room = POST_NMS_TOPN - cnt;   // keep lowest `room` set bits
                    while (room > 0) {
                        unsigned long long lsb = word & (~word + 1ull);
                        outw |= lsb; word ^= lsb; --room;
                    }
                    kb[w] = outw; cnt = POST_NMS_TOPN;
                }
            }
            if (l == 0) {
                #pragma unroll
                for (int w = 0; w < 8; ++w) s_keep[w] = kb[w];
            }
        }
        __syncthreads();

        // ---- Phase 7: scatter masked scores to original order ----
        if (tid < R) {
            int orig = s_order[tid];
            bool kept = (s_keep[tid >> 6] >> (tid & 63)) & 1ull;
            dists_t[k * R + orig] = kept ? s_sc[orig] : 0.0f;
        }
    } else {
        if (tid < R) dists_t[k * R + tid] = 0.0f;
    }

    // ---- Epilogue: last-block ticket, then fused finalize ----
    __syncthreads();                       // all dists_t stores complete (vmcnt drained at barrier)
    if (tid == 0) {
        __threadfence();                   // agent-scope release of dists_t
        unsigned int t = atomicAdd(ticket, 1u);
        s_last = (t == K - 1);
    }
    __syncthreads();
    if (!s_last) return;
    __threadfence();                       // agent-scope acquire before reading others' writes

    // Finalize (threads 0..511): per-row max/first-argmax over K classes.
    if (tid < R) {
        const int r = tid;
        float vmax = dists_t[r];           // kk = 0 column (always zeros)
        int arg = 0;
        for (int kk = 1; kk < K; ++kk) {
            float v = dists_t[kk * R + r]; // coalesced across threads
            if (v > vmax) { vmax = v; arg = kk; }   // first-occurrence argmax
        }
        s_sc[r]    = vmax;                 // reuse as scores_pre
        s_order[r] = arg;                  // reuse as label stash
    }
    __syncthreads();
    if (tid < R) {
        const int r = tid;
        const float vmax = s_sc[r];
        const int arg = s_order[r];
        int cnt = 0;
        for (int j = 0; j < R; ++j) {      // stable descending rank
            float sj = s_sc[j];
            cnt += (sj > vmax) || (sj == vmax && j < r);
        }
        if (cnt < MAX_PER_IMG) {
            bool valid = vmax > SCORE_THRESH_F;
            float4 b = transform_box(rois, deltas, r, arg);
            out[cnt * 5 + 0] = valid ? vmax : 0.0f;
            out[cnt * 5 + 1] = valid ? b.x : 0.0f;
            out[cnt * 5 + 2] = valid ? b.y : 0.0f;
            out[cnt * 5 + 3] = valid ? b.z : 0.0f;
            out[cnt * 5 + 4] = valid ? b.w : 0.0f;
            out[500 + cnt] = (float)arg;   // labels_all
            out[600 + cnt] = (float)r;     // top
        }
    }
}

// ---------------------------------------------------------------------------
extern "C" void kernel_launch(void* const* d_in, const int* in_sizes, int n_in,
                              void* d_out, int out_size, void* d_ws, size_t ws_size,
                              hipStream_t stream) {
    const float* rois   = (const float*)d_in[0];   // [512,4]
    const float* deltas = (const float*)d_in[1];   // [512,324]
    const float* scores = (const float*)d_in[2];   // [512,81]
    float* out = (float*)d_out;                    // 700 floats

    float* dists_t = (float*)d_ws;                 // [K][R] floats
    unsigned int* ticket =
        (unsigned int*)((char*)d_ws + (size_t)K * R * sizeof(float));

    hipMemsetAsync(ticket, 0, sizeof(unsigned int), stream);  // ws is re-poisoned
    nms_all_kernel<<<K, NMS_THREADS, 0, stream>>>(rois, deltas, scores,
                                                  dists_t, ticket, out);
}

// Round 4
// 158.064 us; speedup vs baseline: 2.2161x; 1.0418x over previous
//
#include <hip/hip_runtime.h>
#include <cstdint>
#include <cstddef>

// Mask R-CNN detection post-processing, 5 stream-ordered dispatches (per-phase
// rocprof attribution + coalesced layouts + full-chip bitmatrix):
//   1. transpose:  scores[r][k] -> scores_t[k][r], deltas[r][k] -> deltas_t[k][r]
//   2. rank_boxes: per class stable rank-sort + sorted boxes/scores + validity
//   3. bitmatrix:  648 blocks (class x word): IoU suppression bits -> global
//   4. sweep:      per class wave-cooperative greedy sweep + top-300 cut
//   5. finalize:   per-row max/first-argmax + stable top-100 + output
// All sorts are exact stable ranks (JAX argsort tie-break); IoU uses IEEE f32
// division in reference expression order (bit-exact in R1-R3, absmax 0.0).

#define R 512
#define K 81
#define IM_W_MAX 1332.0f   // IM_W - 1
#define IM_H_MAX 799.0f    // IM_H - 1
#define XFORM_CLIP_F 4.135166556742356f  // log(1000/16)
#define NMS_THRESH_F 0.5f
#define SCORE_THRESH_F 0.001f
#define MAX_PER_IMG 100
#define POST_NMS_TOPN 300

// Box transform for (roi r, class k) from transposed deltas. Arithmetic
// value-identical to rounds 1-3 (verified absmax 0.0).
__device__ __forceinline__ float4 transform_box(const float* __restrict__ rois,
                                                const float4* __restrict__ deltas_t,
                                                int r, int k) {
    float4 roi = ((const float4*)rois)[r];
    float4 d4  = deltas_t[k * R + r];
    float w  = roi.z - roi.x + 1.0f;
    float h  = roi.w - roi.y + 1.0f;
    float cx = roi.x + 0.5f * w;
    float cy = roi.y + 0.5f * h;
    float dx = d4.x / 10.0f;                       // WX
    float dy = d4.y / 10.0f;                       // WY
    float dw = fminf(d4.z / 5.0f, XFORM_CLIP_F);   // WW
    float dh = fminf(d4.w / 5.0f, XFORM_CLIP_F);   // WH
    float pcx = dx * w + cx;
    float pcy = dy * h + cy;
    float pw  = expf(dw) * w;
    float ph  = expf(dh) * h;
    float4 b;
    b.x = fminf(fmaxf(pcx - 0.5f * pw, 0.0f), IM_W_MAX);
    b.y = fminf(fmaxf(pcy - 0.5f * ph, 0.0f), IM_H_MAX);
    b.z = fminf(fmaxf(pcx + 0.5f * pw - 1.0f, 0.0f), IM_W_MAX);
    b.w = fminf(fmaxf(pcy + 0.5f * ph - 1.0f, 0.0f), IM_H_MAX);
    return b;
}

// ---------------------------------------------------------------------------
// 1. Transpose: coalesced reads, scattered writes (fire-and-forget).
// ---------------------------------------------------------------------------
__global__ void __launch_bounds__(256)
transpose_kernel(const float* __restrict__ scores,
                 const float* __restrict__ deltas,
                 float* __restrict__ scores_t,
                 float4* __restrict__ deltas_t) {
    int e = blockIdx.x * 256 + threadIdx.x;
    if (e >= R * K) return;
    int r = e / K, k = e - r * K;
    scores_t[k * R + r] = scores[e];                 // coalesced read
    deltas_t[k * R + r] = ((const float4*)deltas)[e]; // coalesced 16B read
}

// ---------------------------------------------------------------------------
// 2. Per-class stable rank-sort + sorted boxes/scores + class validity.
// ---------------------------------------------------------------------------
__global__ void __launch_bounds__(512)
rank_boxes_kernel(const float* __restrict__ rois,
                  const float4* __restrict__ deltas_t,
                  const float* __restrict__ scores_t,
                  float4* __restrict__ sbox_g,     // [K][R] sorted boxes
                  int* __restrict__ order_g,       // [K][R] order[rank]=orig
                  float* __restrict__ ssc_g,       // [K][R] sorted scores
                  int* __restrict__ valid_g) {     // [K]
    const int k = blockIdx.x, tid = threadIdx.x;
    __shared__ float4 s_sc4[R / 4];
    float* s_sc = (float*)s_sc4;
    __shared__ int   s_order[R];
    __shared__ float s_red[256];

    s_sc[tid] = scores_t[k * R + tid];               // coalesced
    __syncthreads();

    if (tid < 256) s_red[tid] = fmaxf(s_sc[tid], s_sc[tid + 256]);
    __syncthreads();
    for (int s = 128; s > 0; s >>= 1) {
        if (tid < s) s_red[tid] = fmaxf(s_red[tid], s_red[tid + s]);
        __syncthreads();
    }
    const bool valid = (k != 0) && (s_red[0] > SCORE_THRESH_F);  // uniform
    if (tid == 0) valid_g[k] = valid;
    if (!valid) return;

    // Stable descending rank (== jnp.argsort(-s)), b128 LDS reads.
    {
        const float si = s_sc[tid];
        int cnt = 0;
        #pragma unroll 8
        for (int j4 = 0; j4 < R / 4; ++j4) {
            float4 v = s_sc4[j4];
            int jb = j4 * 4;
            cnt += (v.x > si) || (v.x == si && (jb + 0) < tid);
            cnt += (v.y > si) || (v.y == si && (jb + 1) < tid);
            cnt += (v.z > si) || (v.z == si && (jb + 2) < tid);
            cnt += (v.w > si) || (v.w == si && (jb + 3) < tid);
        }
        s_order[cnt] = tid;
    }
    __syncthreads();

    // Boxes/scores at sorted positions.
    {
        int orig = s_order[tid];
        float4 b = transform_box(rois, deltas_t, orig, k);
        sbox_g[k * R + tid]  = b;
        order_g[k * R + tid] = orig;
        ssc_g[k * R + tid]   = s_sc[orig];
    }
}

// ---------------------------------------------------------------------------
// 3. Bitmatrix: block = (class k, word w). supT_g[k][w][i] bit jj set iff
//    j = w*64+jj > i and IoU(i,j) > 0.5 (sorted order). 648 blocks.
// ---------------------------------------------------------------------------
__global__ void __launch_bounds__(256)
bitmatrix_kernel(const float4* __restrict__ sbox_g,
                 const int* __restrict__ valid_g,
                 unsigned long long* __restrict__ supT_g) {
    const int b = blockIdx.x;
    const int k = b >> 3;          // b / 8
    const int w = b & 7;
    const int tid = threadIdx.x;
    if (!valid_g[k]) return;       // uniform; sweep also exits for invalid k

    __shared__ float4 s_sbox[R];
    __shared__ float  s_area[R];
    for (int i = tid; i < R; i += 256) {
        float4 bx = sbox_g[k * R + i];
        s_sbox[i] = bx;
        s_area[i] = (bx.z - bx.x + 1.0f) * (bx.w - bx.y + 1.0f);
    }
    __syncthreads();

    const int jbase = w * 64;
    #pragma unroll
    for (int rep = 0; rep < 2; ++rep) {
        const int i = tid + rep * 256;
        const int d = i - jbase;   // bits jj <= d are j <= i: masked out
        unsigned long long mask =
            (d < 0) ? ~0ull : ((d >= 63) ? 0ull : (~0ull << (d + 1)));
        unsigned long long bits = 0ull;
        if (mask) {                // waves fully past the word skip entirely
            const float4 bi = s_sbox[i];
            const float  ai = s_area[i];
            #pragma unroll 8
            for (int jj = 0; jj < 64; ++jj) {
                float4 bj = s_sbox[jbase + jj];   // broadcast LDS read
                float  aj = s_area[jbase + jj];
                float xx1 = fmaxf(bi.x, bj.x);
                float yy1 = fmaxf(bi.y, bj.y);
                float xx2 = fminf(bi.z, bj.z);
                float yy2 = fminf(bi.w, bj.w);
                float iw = fmaxf(xx2 - xx1 + 1.0f, 0.0f);
                float ih = fmaxf(yy2 - yy1 + 1.0f, 0.0f);
                float inter = iw * ih;
                float iou = inter / (ai + aj - inter);   // IEEE div, ref order
                bits |= (unsigned long long)(iou > NMS_THRESH_F) << jj;
            }
        }
        supT_g[k * 4096 + w * 512 + i] = bits & mask;    // coalesced u64 write
    }
}

// ---------------------------------------------------------------------------
// 4. Sweep: per class, bulk-load 32 KB bitmatrix -> LDS, wave-0 register
//    sweep (verified R3 phase-6 logic), top-300 cut, masked-score scatter.
// ---------------------------------------------------------------------------
__global__ void __launch_bounds__(256)
sweep_kernel(const unsigned long long* __restrict__ supT_g,
             const int* __restrict__ order_g,
             const float* __restrict__ ssc_g,
             const int* __restrict__ valid_g,
             float* __restrict__ dists_t) {       // [K][R]
    const int k = blockIdx.x, tid = threadIdx.x;
    if (!valid_g[k]) {
        for (int i = tid; i < R; i += 256) dists_t[k * R + i] = 0.0f;
        return;
    }
    __shared__ unsigned long long s_supT[8 * R];  // [w*512 + i], 32 KB
    __shared__ unsigned long long s_keep[8];

    {   // bulk load, 16B per thread-iter, coalesced
        const ulonglong2* src = (const ulonglong2*)(supT_g + (size_t)k * 4096);
        ulonglong2* dst = (ulonglong2*)s_supT;
        #pragma unroll
        for (int t = 0; t < 8; ++t) dst[tid + t * 256] = src[tid + t * 256];
    }
    __syncthreads();

    if (tid < 64) {
        const int l = tid;
        unsigned long long kb[8];
        #pragma unroll
        for (int w = 0; w < 8; ++w) kb[w] = ~0ull;

        #pragma unroll
        for (int wb = 0; wb < 8; ++wb) {
            unsigned long long rrow[8];
            #pragma unroll
            for (int w = 0; w < 8; ++w)
                rrow[w] = (w >= wb) ? s_supT[w * R + (wb * 64 + l)] : 0ull;

            const unsigned int r_lo = (unsigned int)(rrow[wb] & 0xffffffffull);
            const unsigned int r_hi = (unsigned int)(rrow[wb] >> 32);

            // Intra-block serial sweep over still-alive bits (wave-uniform).
            unsigned long long cur = kb[wb];
            unsigned long long m = cur;
            while (m) {
                int bit = __builtin_ctzll(m);
                unsigned long long row =
                    ((unsigned long long)(unsigned int)__builtin_amdgcn_readlane((int)r_hi, bit) << 32) |
                     (unsigned long long)(unsigned int)__builtin_amdgcn_readlane((int)r_lo, bit);
                m &= m - 1;
                cur &= ~row;
                m   &= ~row;
            }
            kb[wb] = cur;

            // Inter-block pruning: OR of kept rows' future words.
            #pragma unroll
            for (int w = wb + 1; w < 8; ++w) {
                unsigned long long contrib = ((cur >> l) & 1ull) ? rrow[w] : 0ull;
                #pragma unroll
                for (int off = 32; off > 0; off >>= 1)
                    contrib |= __shfl_xor(contrib, off, 64);
                kb[w] &= ~contrib;
            }
        }

        // cumsum(keep) <= 300 cut, sorted-rank order.
        int total = 0;
        #pragma unroll
        for (int w = 0; w < 8; ++w) total += __popcll(kb[w]);
        if (total > POST_NMS_TOPN) {
            int cnt = 0;
            #pragma unroll
            for (int w = 0; w < 8; ++w) {
                int pc = __popcll(kb[w]);
                if (cnt + pc <= POST_NMS_TOPN) { cnt += pc; continue; }
                unsigned long long word = kb[w], outw = 0ull;
                int room = POST_NMS_TOPN - cnt;
                while (room > 0) {
                    unsigned long long lsb = word & (~word + 1ull);
                    outw |= lsb; word ^= lsb; --room;
                }
                kb[w] = outw; cnt = POST_NMS_TOPN;
            }
        }
        if (l == 0) {
            #pragma unroll
            for (int w = 0; w < 8; ++w) s_keep[w] = kb[w];
        }
    }
    __syncthreads();

    for (int rk = tid; rk < R; rk += 256) {
        bool kept = (s_keep[rk >> 6] >> (rk & 63)) & 1ull;
        dists_t[k * R + order_g[k * R + rk]] = kept ? ssc_g[k * R + rk] : 0.0f;
    }
}

// ---------------------------------------------------------------------------
// 5. Finalize: per-row max/first-argmax, stable top-100 rank, output write.
//    Output (700 floats): [0..499] out(100x5), [500..599] labels, [600..699] top.
// ---------------------------------------------------------------------------
__global__ void __launch_bounds__(512)
finalize_kernel(const float* __restrict__ dists_t,
                const float* __restrict__ rois,
                const float4* __restrict__ deltas_t,
                float* __restrict__ out) {
    const int r = threadIdx.x;
    __shared__ float4 s_pre4[R / 4];
    float* s_pre = (float*)s_pre4;

    float vmax = dists_t[r];          // kk = 0 column (always zeros)
    int arg = 0;
    #pragma unroll 8
    for (int kk = 1; kk < K; ++kk) {
        float v = dists_t[kk * R + r];           // coalesced
        if (v > vmax) { vmax = v; arg = kk; }    // first-occurrence argmax
    }
    s_pre[r] = vmax;
    __syncthreads();

    int cnt = 0;
    #pragma unroll 8
    for (int j4 = 0; j4 < R / 4; ++j4) {         // stable descending rank
        float4 v = s_pre4[j4];
        int jb = j4 * 4;
        cnt += (v.x > vmax) || (v.x == vmax && (jb + 0) < r);
        cnt += (v.y > vmax) || (v.y == vmax && (jb + 1) < r);
        cnt += (v.z > vmax) || (v.z == vmax && (jb + 2) < r);
        cnt += (v.w > vmax) || (v.w == vmax && (jb + 3) < r);
    }
    if (cnt < MAX_PER_IMG) {
        bool valid = vmax > SCORE_THRESH_F;
        float4 b = transform_box(rois, deltas_t, r, arg);
        out[cnt * 5 + 0] = valid ? vmax : 0.0f;
        out[cnt * 5 + 1] = valid ? b.x : 0.0f;
        out[cnt * 5 + 2] = valid ? b.y : 0.0f;
        out[cnt * 5 + 3] = valid ? b.z : 0.0f;
        out[cnt * 5 + 4] = valid ? b.w : 0.0f;
        out[500 + cnt] = (float)arg;   // labels_all
        out[600 + cnt] = (float)r;     // top
    }
}

// ---------------------------------------------------------------------------
extern "C" void kernel_launch(void* const* d_in, const int* in_sizes, int n_in,
                              void* d_out, int out_size, void* d_ws, size_t ws_size,
                              hipStream_t stream) {
    const float* rois   = (const float*)d_in[0];   // [512,4]
    const float* deltas = (const float*)d_in[1];   // [512,324]
    const float* scores = (const float*)d_in[2];   // [512,81]
    float* out = (float*)d_out;                    // 700 floats

    char* ws = (char*)d_ws;                        // ~4.5 MB used
    float* scores_t = (float*)(ws + 0);                        // 165,888 B
    float* dists_t  = (float*)(ws + 165888);                   // 165,888 B
    float* ssc_g    = (float*)(ws + 331776);                   // 165,888 B
    int*   order_g  = (int*)  (ws + 497664);                   // 165,888 B
    int*   valid_g  = (int*)  (ws + 663552);                   //     512 B
    float4* deltas_t = (float4*)(ws + 664064);                 // 663,552 B
    float4* sbox_g   = (float4*)(ws + 1327616);                // 663,552 B
    unsigned long long* supT_g = (unsigned long long*)(ws + 1991168); // 2,654,208 B

    transpose_kernel <<<(R * K + 255) / 256, 256, 0, stream>>>(scores, deltas,
                                                               scores_t, deltas_t);
    rank_boxes_kernel<<<K, 512, 0, stream>>>(rois, deltas_t, scores_t,
                                             sbox_g, order_g, ssc_g, valid_g);
    bitmatrix_kernel <<<K * 8, 256, 0, stream>>>(sbox_g, valid_g, supT_g);
    sweep_kernel     <<<K, 256, 0, stream>>>(supT_g, order_g, ssc_g, valid_g, dists_t);
    finalize_kernel  <<<1, 512, 0, stream>>>(dists_t, rois, deltas_t, out);
}